// Round 19
// baseline (255.460 us; speedup 1.0000x reference)
//
#include <hip/hip_runtime.h>
#include <hip/hip_bf16.h>
#include <cmath>

// Problem constants
#define TT 3
#define HH 64
#define WW 64
#define NPIX 4096       // 64*64
#define NHEADS 4
#define CHD 64
#define DIMD 256
#define PS 7
#define WS 9
#define WSH 4
#define KS 16
#define KA 8
#define NG 32           // grid points per dim (stride 2)
#define QTOT 3072       // T*32*32
#define NOFF 81
#define SCALE 0.125f

// Workspace offsets (floats)
#define OFF_DW   ((size_t)0)                 // [3type][3t][256][4096] = 9,437,184
#define OFF_Q    ((size_t)9437184)           // [t][ch][pix] 3,145,728
#define OFF_K    ((size_t)12582912)          // [t][ch][pix]
#define OFF_V    ((size_t)15728640)          // [t][pix][ch]
#define OFF_D    ((size_t)18874368)          // [81][12][4096] = 3,981,312
#define OFF_DG   ((size_t)22855680)          // [12288][81] = 995,328
#define OFF_ATTN ((size_t)23851008)          // [12288][8]
#define OFF_INDS ((size_t)23949312)          // [12288][8] int
#define OFF_VACC ((size_t)24047616)          // [t][pix][256] 3,145,728
// total ~27M floats = 108.8 MB

__device__ __forceinline__ int reflect_i(int i, int n) {
  i = i < 0 ? -i : i;
  return i >= n ? 2 * (n - 1) - i : i;
}

// K1: depthwise 3x3, zero padding, for q/k/v in one pass.
__global__ void k_dw(const float* __restrict__ vid,
                     const float* __restrict__ qdw, const float* __restrict__ kdw,
                     const float* __restrict__ vdw, float* __restrict__ dw) {
  int plane = blockIdx.x;          // t*256+ch
  int ch = plane & 255;
  const float* src = vid + (size_t)plane * NPIX;
  float wq[9], wk[9], wv[9];
#pragma unroll
  for (int i = 0; i < 9; i++) { wq[i] = qdw[ch*9+i]; wk[i] = kdw[ch*9+i]; wv[i] = vdw[ch*9+i]; }
  int x = threadIdx.x, ty = threadIdx.y;   // (64,4)
  for (int yb = 0; yb < 16; ++yb) {
    int y = yb * 4 + ty;
    float aq = 0, ak = 0, av = 0;
#pragma unroll
    for (int a = 0; a < 3; a++) {
      int yy = y + a - 1;
      if (yy < 0 || yy >= HH) continue;
#pragma unroll
      for (int b = 0; b < 3; b++) {
        int xx = x + b - 1;
        if (xx < 0 || xx >= WW) continue;
        float xv = src[yy * WW + xx];
        aq += xv * wq[a*3+b]; ak += xv * wk[a*3+b]; av += xv * wv[a*3+b];
      }
    }
    size_t o = (size_t)plane * NPIX + y * WW + x;
    dw[o] = aq;
    dw[(size_t)3145728 + o] = ak;
    dw[(size_t)6291456 + o] = av;
  }
}

// K2 v7 (R16 best): 64x64 tile, 4x4 reg tile, dbuf + depth-2 reg pipeline.
// grid (64 pixtiles, 4 otiles, 9=type*3+t), block 256
__global__ void k_pw(const float* __restrict__ dw,
                     const float* __restrict__ qpw, const float* __restrict__ qb,
                     const float* __restrict__ kpw, const float* __restrict__ kb,
                     const float* __restrict__ vpw, const float* __restrict__ vb,
                     float* __restrict__ qo, float* __restrict__ ko, float* __restrict__ vo) {
  int type = blockIdx.z / 3, t = blockIdx.z % 3;
  const float* W   = type == 0 ? qpw : (type == 1 ? kpw : vpw);
  const float* bia = type == 0 ? qb  : (type == 1 ? kb  : vb);
  const float* A = dw + (size_t)type * 3145728 + (size_t)t * 1048576;  // [256][4096]
  int p0 = blockIdx.x * 64, o0 = blockIdx.y * 64;

  __shared__ float sW[2][16][68];   // [buf][k][o]
  __shared__ float sA[2][16][68];   // [buf][k][p]

  int tid = threadIdx.x;
  int ty = tid >> 4, tx = tid & 15;
  int wrow = tid >> 2, wcol = tid & 3;     // W staging: row 0..63, f4-col 0..3
  int arow = tid >> 4, acol = tid & 15;    // A staging: k-row 0..15, f4-px 0..15

  const float* Wp = &W[(size_t)(o0 + wrow) * 256 + wcol * 4];
  const float* Ap = &A[(size_t)arow * NPIX + p0 + acol * 4];

  {
    float4 w4 = *(const float4*)Wp;
    float4 a4 = *(const float4*)Ap;
    sW[0][wcol * 4 + 0][wrow] = w4.x;
    sW[0][wcol * 4 + 1][wrow] = w4.y;
    sW[0][wcol * 4 + 2][wrow] = w4.z;
    sW[0][wcol * 4 + 3][wrow] = w4.w;
    *(float4*)&sA[0][arow][acol * 4] = a4;
  }
  float4 wH = *(const float4*)(Wp + 16);
  float4 aH = *(const float4*)(Ap + (size_t)16 * NPIX);
  __syncthreads();

  float acc[4][4] = {};

#pragma unroll 1
  for (int k0 = 0; k0 < 256; k0 += 16) {
    const int cur = (k0 >> 4) & 1;
    float4 wN, aN;
    if (k0 + 32 < 256) {
      wN = *(const float4*)(Wp + k0 + 32);
      aN = *(const float4*)(Ap + (size_t)(k0 + 32) * NPIX);
    }
#pragma unroll
    for (int kk = 0; kk < 16; kk++) {
      float4 av = *(const float4*)&sW[cur][kk][ty * 4];
      float4 bv = *(const float4*)&sA[cur][kk][tx * 4];
      acc[0][0] += av.x * bv.x; acc[0][1] += av.x * bv.y; acc[0][2] += av.x * bv.z; acc[0][3] += av.x * bv.w;
      acc[1][0] += av.y * bv.x; acc[1][1] += av.y * bv.y; acc[1][2] += av.y * bv.z; acc[1][3] += av.y * bv.w;
      acc[2][0] += av.z * bv.x; acc[2][1] += av.z * bv.y; acc[2][2] += av.z * bv.z; acc[2][3] += av.z * bv.w;
      acc[3][0] += av.w * bv.x; acc[3][1] += av.w * bv.y; acc[3][2] += av.w * bv.z; acc[3][3] += av.w * bv.w;
    }
    if (k0 + 16 < 256) {
      const int nxt = cur ^ 1;
      sW[nxt][wcol * 4 + 0][wrow] = wH.x;
      sW[nxt][wcol * 4 + 1][wrow] = wH.y;
      sW[nxt][wcol * 4 + 2][wrow] = wH.z;
      sW[nxt][wcol * 4 + 3][wrow] = wH.w;
      *(float4*)&sA[nxt][arow][acol * 4] = aH;
      __syncthreads();
      wH = wN; aH = aN;
    }
  }

  int obase = o0 + ty * 4, pbase = p0 + tx * 4;
  if (type == 2) {
#pragma unroll
    for (int j = 0; j < 4; j++) {
      float4 ov = make_float4(acc[0][j] + bia[obase + 0],
                              acc[1][j] + bia[obase + 1],
                              acc[2][j] + bia[obase + 2],
                              acc[3][j] + bia[obase + 3]);
      *(float4*)&vo[((size_t)t * NPIX + pbase + j) * 256 + obase] = ov;
    }
  } else {
    float* dst = (type == 0) ? qo : ko;
    float sc = (type == 0) ? SCALE : 1.0f;
#pragma unroll
    for (int i = 0; i < 4; i++) {
      float bb = bia[obase + i];
      float4 ov = make_float4((acc[i][0] + bb) * sc, (acc[i][1] + bb) * sc,
                              (acc[i][2] + bb) * sc, (acc[i][3] + bb) * sc);
      *(float4*)&dst[((size_t)t * 256 + obase + i) * NPIX + pbase] = ov;
    }
  }
}

// K3a v2: q in REGISTERS; K staged per dyi into [cc][x] float4 LDS.
// grid 768 = th*64 + y, block 256
__global__ void k_dist(const float* __restrict__ q, const float* __restrict__ k,
                       float* __restrict__ D) {
  int b = blockIdx.x;
  int y = b & 63, th = b >> 6;
  int t = th >> 2, h = th & 3;
  __shared__ float4 sK4[16][64];   // [cc][x]
  int tid = threadIdx.x;
  int x = tid & 63, w = tid >> 6;
  const float* qp = q + ((size_t)t * 256 + h * 64) * NPIX + y * WW;
  const float* kp = k + ((size_t)t * 256 + h * 64) * NPIX;

  float4 qv[16];
#pragma unroll
  for (int cc = 0; cc < 16; cc++) {
    qv[cc].x = qp[(size_t)(4 * cc + 0) * NPIX + x];
    qv[cc].y = qp[(size_t)(4 * cc + 1) * NPIX + x];
    qv[cc].z = qp[(size_t)(4 * cc + 2) * NPIX + x];
    qv[cc].w = qp[(size_t)(4 * cc + 3) * NPIX + x];
  }

  for (int dyi = 0; dyi < 9; ++dyi) {
    int yk = reflect_i(y + dyi - 4, HH);
    __syncthreads();
    {
      int cc = tid >> 6;
      const float* kr = kp + (size_t)yk * WW;
#pragma unroll
      for (int r = 0; r < 4; r++) {
        int c4 = (cc + 4 * r) * 4;
        float4 kv;
        kv.x = kr[(size_t)(c4 + 0) * NPIX + x];
        kv.y = kr[(size_t)(c4 + 1) * NPIX + x];
        kv.z = kr[(size_t)(c4 + 2) * NPIX + x];
        kv.w = kr[(size_t)(c4 + 3) * NPIX + x];
        sK4[cc + 4 * r][x] = kv;
      }
    }
    __syncthreads();
    for (int dxi = w; dxi < 9; dxi += 4) {
      int xk = reflect_i(x + dxi - 4, WW);
      float s0 = 0.f, s1 = 0.f, s2 = 0.f, s3 = 0.f;
#pragma unroll
      for (int cc = 0; cc < 16; cc++) {
        float4 kv = sK4[cc][xk];
        s0 += qv[cc].x * kv.x;
        s1 += qv[cc].y * kv.y;
        s2 += qv[cc].z * kv.z;
        s3 += qv[cc].w * kv.w;
      }
      D[((size_t)(dyi * 9 + dxi) * 12 + th) * NPIX + y * WW + x] = (s0 + s1) + (s2 + s3);
    }
  }
}

// K3b v2: separable 7x7 reflected box sum. grid (12, 81), block 256
__global__ void k_box(const float* __restrict__ D, float* __restrict__ DG) {
  int th = blockIdx.x, n = blockIdx.y;
  int t = th >> 2, h = th & 3;
  __shared__ float sD[4096];
  __shared__ float sR[64][33];   // [y][gx], padded
  int tid = threadIdx.x;
  const float* Dp = D + ((size_t)n * 12 + th) * NPIX;
  for (int i = tid; i < 4096; i += 256) sD[i] = Dp[i];
  __syncthreads();
  for (int e = tid; e < 2048; e += 256) {
    int y = e >> 5, gx = e & 31;
    int xq = gx * 2;
    const float* row = sD + y * WW;
    float s = 0.f;
#pragma unroll
    for (int px = 0; px < 7; px++) {
      int rx = xq + px; rx = rx >= WW ? 126 - rx : rx;
      s += row[rx];
    }
    sR[y][gx] = s;
  }
  __syncthreads();
  for (int qi = tid; qi < 1024; qi += 256) {
    int gy = qi >> 5, gx = qi & 31;
    int yq = gy * 2;
    float s = 0.f;
#pragma unroll
    for (int py = 0; py < 7; py++) {
      int ry = yq + py; ry = ry >= HH ? 126 - ry : ry;
      s += sR[ry][gx];
    }
    DG[((size_t)h * QTOT + t * 1024 + qi) * NOFF + n] = s;
  }
}

// K3c v2: wave-parallel top-16 + softmax. grid 3072, block 256
__global__ void k_topk(const float* __restrict__ DG, float* __restrict__ attn,
                       int* __restrict__ inds) {
  int lane = threadIdx.x & 63;
  int r = blockIdx.x * 4 + (threadIdx.x >> 6);
  const float* row = DG + (size_t)r * NOFF;

  float v0 = row[lane];
  float v1 = (lane < NOFF - 64) ? row[64 + lane] : 0.f;

  auto mono = [](float f) -> unsigned {
    unsigned b = __float_as_uint(f);
    return (b & 0x80000000u) ? ~b : (b | 0x80000000u);
  };
  unsigned long long k0 = ((unsigned long long)mono(v0) << 7) | (unsigned)(127 - lane);
  unsigned long long k1 = (lane < NOFF - 64)
      ? (((unsigned long long)mono(v1) << 7) | (unsigned)(127 - 64 - lane))
      : 0ull;

  float vals[KS]; int idx[KS];
#pragma unroll
  for (int s = 0; s < KS; s++) {
    unsigned long long k = k0 > k1 ? k0 : k1;
#pragma unroll
    for (int m = 32; m >= 1; m >>= 1) {
      unsigned long long o = __shfl_xor(k, m, 64);
      if (o > k) k = o;
    }
    int wi = 127 - (int)(k & 127);
    unsigned mb = (unsigned)(k >> 7);
    unsigned vb = (mb & 0x80000000u) ? (mb ^ 0x80000000u) : ~mb;
    vals[s] = __uint_as_float(vb);
    idx[s] = wi;
    if (wi == lane) k0 = 0ull;
    else if (wi == 64 + lane) k1 = 0ull;
  }

  if (lane == 0) {
    float m = vals[0], den = 0.f, e[KS];
#pragma unroll
    for (int s = 0; s < KS; s++) { e[s] = expf(vals[s] - m); den += e[s]; }
    float inv = 1.f / den;
#pragma unroll
    for (int s = 0; s < KA; s++) {
      attn[(size_t)r * KA + s] = e[s] * inv;
      inds[(size_t)r * KA + s] = idx[s];
    }
  }
}

// K4 v8: gather with WEIGHT-MAP COLLAPSE.
// Key identity: col = refl(2g+dx+px) = refl(x+dx) (indep of g); row = refl(y+dy)
// or refl(yr+dy) (indep of gy). All covering queries' weights for the same
// selected (dy,dx) hit the SAME v pixel -> sum weights per unique cell first
// (16x16 reflected window, LDS atomic), then one weighted v-read per cell.
// grid 3072 (XCD-swizzled) -> (xg, y, t); block 256 = 4 waves (wave = one x).
__global__ void k_agg(const float* __restrict__ v, const float* __restrict__ attn,
                      const int* __restrict__ inds, float* __restrict__ vacc) {
  int bid = blockIdx.x;
  int swz = (bid & 7) * 384 + (bid >> 3);
  int xg = swz & 15, y = (swz >> 4) & 63, t = swz >> 10;
  int x0 = xg * 4;

  int yb = max(0, y - 8);
  int yr = 126 - y;

  // y cover (identical enumeration to v7)
  int g0 = max(0, (y - 5) >> 1), g1 = y >> 1;
  int ndir = g1 - g0 + 1;
  int r0y = (yr - 5) >> 1;
  int ny = ndir + (y >= 58 ? (min(31, yr >> 1) - r0y + 1) : 0);

  __shared__ float wmap[4][4][257];  // [xi][h][cell], padded (h-stride 257 -> distinct banks)
  __shared__ int   lst[4][4][260];   // compacted cell ids, padded
  __shared__ int   cnt[4][4];

  int tid = threadIdx.x;
  // zero
  for (int i = tid; i < 4 * 4 * 257; i += 256) ((float*)wmap)[i] = 0.f;
  if (tid < 16) ((int*)cnt)[tid] = 0;
  __syncthreads();

  // build: e = ((xi*4 + h)*ny + iy)*8 + gs
  int total = 16 * ny * 8;
  for (int e = tid; e < total; e += 256) {
    int gs = e & 7;
    int r = e >> 3;
    int iy = r % ny; r /= ny;
    int h = r & 3, xi = r >> 2;
    int x = x0 + xi;
    int a0 = max(0, (x - 5) >> 1), a1 = x >> 1;
    int ndx = a1 - a0 + 1;
    int xr = 126 - x;
    int b0x = (xr - 5) >> 1, b1x = min(31, xr >> 1);
    int nrx = (x >= 58) ? (b1x - b0x + 1) : 0;
    if (gs >= ndx + nrx) continue;
    int g, colb;
    if (gs < ndx) { g = a0 + gs; colb = x; }
    else          { g = b0x + (gs - ndx); colb = xr; }
    int gy, rowb;
    if (iy < ndir) { gy = g0 + iy; rowb = y; }
    else           { gy = r0y + (iy - ndir); rowb = yr; }
    size_t rq = (size_t)(h * QTOT + t * 1024 + gy * 32 + g);
    float4 w0 = *(const float4*)(attn + rq * KA);
    float4 w1 = *(const float4*)(attn + rq * KA + 4);
    int4 i0 = *(const int4*)(inds + rq * KA);
    int4 i1 = *(const int4*)(inds + rq * KA + 4);
    int ids[8] = {i0.x, i0.y, i0.z, i0.w, i1.x, i1.y, i1.z, i1.w};
    float ww[8] = {w0.x, w0.y, w0.z, w0.w, w1.x, w1.y, w1.z, w1.w};
    int xb = max(0, x - 8);
#pragma unroll
    for (int n = 0; n < 8; n++) {
      int dy = ids[n] / 9 - 4, dx = ids[n] % 9 - 4;
      int rr = reflect_i(rowb + dy, HH);
      int cc = reflect_i(colb + dx, WW);
      int cell = ((rr - yb) << 4) | (cc - xb);
      atomicAdd(&wmap[xi][h][cell], ww[n]);
    }
  }
  __syncthreads();

  // compact nonzero cells (weights strictly positive -> exact detection)
  for (int e = tid; e < 4096; e += 256) {
    int cell = e & 255, h = (e >> 8) & 3, xi = e >> 10;
    float wv_ = wmap[xi][h][cell];
    if (wv_ != 0.f) {
      int pos = atomicAdd(&cnt[xi][h], 1);
      lst[xi][h][pos] = cell;
    }
  }
  __syncthreads();

  // gather: wave wv -> x = x0+wv; lane covers 4 channels, h = lane>>4
  int wv = tid >> 6, lane = tid & 63;
  int x = x0 + wv;
  int h = lane >> 4;
  int xb = max(0, x - 8);
  const char* vB = (const char*)v + (size_t)t * ((size_t)NPIX * DIMD * 4)
                   + (unsigned)(lane * 16);
  int len = cnt[wv][h];
  int maxlen = max(max(cnt[wv][0], cnt[wv][1]), max(cnt[wv][2], cnt[wv][3]));
  int rowbase = yb * WW + xb;

  float4 acc = make_float4(0.f, 0.f, 0.f, 0.f);
#pragma unroll 4
  for (int i = 0; i < maxlen; ++i) {
    int ii = min(i, len - 1);
    int cell = lst[wv][h][ii];
    float w = (i < len) ? wmap[wv][h][cell] : 0.f;
    unsigned off = (unsigned)((rowbase + ((cell >> 4) << 6) + (cell & 15)) << 10);
    float4 vv = *(const float4*)(vB + off);
    acc.x += w * vv.x; acc.y += w * vv.y; acc.z += w * vv.z; acc.w += w * vv.w;
  }
  float* oP = vacc + ((size_t)t * NPIX + (size_t)y * WW + x) * DIMD + lane * 4;
  *(float4*)oP = acc;
}

// coverage count for one axis (how many (g,p) pairs map to index i)
__device__ __forceinline__ int cov_count(int i) {
  int d = (i >> 1) - max(0, (i - 5) >> 1) + 1;
  if (i >= 58) { int r = 126 - i; d += min(31, r >> 1) - ((r - 5) >> 1) + 1; }
  return d;
}

// K5 v4: final projection, 64x64 tile, 4x4 reg tile, dbuf rolled.
// grid (192, 4), block 256
__global__ void k_proj(const float* __restrict__ vacc,
                       const float* __restrict__ pw, const float* __restrict__ pb,
                       float* __restrict__ out) {
  int p0 = blockIdx.x * 64;  // global pixel (t*4096 + y*64 + x)
  int d0 = blockIdx.y * 64;

  __shared__ float sW[2][16][68];   // [buf][k][d]
  __shared__ float sV[2][16][68];   // [buf][k][p]

  int tid = threadIdx.x;
  int ty = tid >> 4, tx = tid & 15;
  int row = tid >> 2, col = tid & 3;   // staging: row 0..63, f4-col 0..3

  const float* Wp = &pw[(size_t)(d0 + row) * 256 + col * 4];
  const float* Vp = &vacc[(size_t)(p0 + row) * 256 + col * 4];

  {
    float4 w4 = *(const float4*)Wp;
    float4 v4 = *(const float4*)Vp;
    sW[0][col * 4 + 0][row] = w4.x;
    sW[0][col * 4 + 1][row] = w4.y;
    sW[0][col * 4 + 2][row] = w4.z;
    sW[0][col * 4 + 3][row] = w4.w;
    sV[0][col * 4 + 0][row] = v4.x;
    sV[0][col * 4 + 1][row] = v4.y;
    sV[0][col * 4 + 2][row] = v4.z;
    sV[0][col * 4 + 3][row] = v4.w;
  }
  __syncthreads();

  float acc[4][4] = {};

#pragma unroll 1
  for (int k0 = 0; k0 < 256; k0 += 16) {
    const int cur = (k0 >> 4) & 1;
    const bool hn = (k0 + 16) < 256;
    float4 w4n, v4n;
    if (hn) {
      w4n = *(const float4*)(Wp + k0 + 16);
      v4n = *(const float4*)(Vp + k0 + 16);
    }
#pragma unroll
    for (int kk = 0; kk < 16; kk++) {
      float4 av = *(const float4*)&sW[cur][kk][ty * 4];
      float4 bv = *(const float4*)&sV[cur][kk][tx * 4];
      acc[0][0] += av.x * bv.x; acc[0][1] += av.x * bv.y; acc[0][2] += av.x * bv.z; acc[0][3] += av.x * bv.w;
      acc[1][0] += av.y * bv.x; acc[1][1] += av.y * bv.y; acc[1][2] += av.y * bv.z; acc[1][3] += av.y * bv.w;
      acc[2][0] += av.z * bv.x; acc[2][1] += av.z * bv.y; acc[2][2] += av.z * bv.z; acc[2][3] += av.z * bv.w;
      acc[3][0] += av.w * bv.x; acc[3][1] += av.w * bv.y; acc[3][2] += av.w * bv.z; acc[3][3] += av.w * bv.w;
    }
    if (hn) {
      const int nxt = cur ^ 1;
      sW[nxt][col * 4 + 0][row] = w4n.x;
      sW[nxt][col * 4 + 1][row] = w4n.y;
      sW[nxt][col * 4 + 2][row] = w4n.z;
      sW[nxt][col * 4 + 3][row] = w4n.w;
      sV[nxt][col * 4 + 0][row] = v4n.x;
      sV[nxt][col * 4 + 1][row] = v4n.y;
      sV[nxt][col * 4 + 2][row] = v4n.z;
      sV[nxt][col * 4 + 3][row] = v4n.w;
      __syncthreads();
    }
  }

  int dbase = d0 + ty * 4, pbase = p0 + tx * 4;
  float izv[4];
#pragma unroll
  for (int j = 0; j < 4; j++) {
    int pl = (pbase + j) & 4095;
    int yy = pl >> 6, xx = pl & 63;
    izv[j] = 1.0f / (float)(cov_count(yy) * cov_count(xx));
  }
  int t = pbase >> 12, pl0 = pbase & 4095;
#pragma unroll
  for (int i = 0; i < 4; i++) {
    int d = dbase + i;
    float bb = pb[d];
    float4 ov = make_float4(acc[i][0] * izv[0] + bb, acc[i][1] * izv[1] + bb,
                            acc[i][2] * izv[2] + bb, acc[i][3] * izv[3] + bb);
    *(float4*)&out[((size_t)t * 256 + d) * NPIX + pl0] = ov;
  }
}

extern "C" void kernel_launch(void* const* d_in, const int* in_sizes, int n_in,
                              void* d_out, int out_size, void* d_ws, size_t ws_size,
                              hipStream_t stream) {
  const float* vid = (const float*)d_in[0];
  const float* qdw = (const float*)d_in[1];
  const float* qpw = (const float*)d_in[2];
  const float* qb  = (const float*)d_in[3];
  const float* kdw = (const float*)d_in[4];
  const float* kpw = (const float*)d_in[5];
  const float* kb  = (const float*)d_in[6];
  const float* vdw = (const float*)d_in[7];
  const float* vpw = (const float*)d_in[8];
  const float* vb  = (const float*)d_in[9];
  const float* pw  = (const float*)d_in[10];
  const float* pb  = (const float*)d_in[11];
  float* out = (float*)d_out;
  float* ws = (float*)d_ws;

  float* dwb  = ws + OFF_DW;
  float* qbuf = ws + OFF_Q;
  float* kbuf = ws + OFF_K;
  float* vbuf = ws + OFF_V;
  float* Dbuf = ws + OFF_D;
  float* DG   = ws + OFF_DG;
  float* attn = ws + OFF_ATTN;
  int*   inds = (int*)(ws + OFF_INDS);
  float* vacc = ws + OFF_VACC;

  k_dw<<<dim3(768), dim3(64, 4), 0, stream>>>(vid, qdw, kdw, vdw, dwb);
  k_pw<<<dim3(64, 4, 9), 256, 0, stream>>>(dwb, qpw, qb, kpw, kb, vpw, vb,
                                           qbuf, kbuf, vbuf);
  k_dist<<<dim3(768), 256, 0, stream>>>(qbuf, kbuf, Dbuf);
  k_box<<<dim3(12, 81), 256, 0, stream>>>(Dbuf, DG);
  k_topk<<<dim3(3072), 256, 0, stream>>>(DG, attn, inds);
  k_agg<<<dim3(3072), 256, 0, stream>>>(vbuf, attn, inds, vacc);
  k_proj<<<dim3(192, 4), 256, 0, stream>>>(vacc, pw, pb, out);
}

// Round 20
// 244.298 us; speedup vs baseline: 1.0457x; 1.0457x over previous
//
#include <hip/hip_runtime.h>
#include <hip/hip_bf16.h>
#include <cmath>

// Problem constants
#define TT 3
#define HH 64
#define WW 64
#define NPIX 4096       // 64*64
#define NHEADS 4
#define CHD 64
#define DIMD 256
#define PS 7
#define WS 9
#define WSH 4
#define KS 16
#define KA 8
#define NG 32           // grid points per dim (stride 2)
#define QTOT 3072       // T*32*32
#define NOFF 81
#define SCALE 0.125f

// Workspace offsets (floats)
#define OFF_DW   ((size_t)0)                 // [3type][3t][256][4096] = 9,437,184
#define OFF_Q    ((size_t)9437184)           // [t][ch][pix] 3,145,728
#define OFF_K    ((size_t)12582912)          // [t][ch][pix]
#define OFF_V    ((size_t)15728640)          // [t][pix][ch]
#define OFF_D    ((size_t)18874368)          // [81][12][4096] = 3,981,312
#define OFF_DG   ((size_t)22855680)          // [12288][81] = 995,328
#define OFF_ATTN ((size_t)23851008)          // [12288][8]
#define OFF_INDS ((size_t)23949312)          // [12288][8] int
#define OFF_VACC ((size_t)24047616)          // [t][pix][256] 3,145,728
// total ~27M floats = 108.8 MB

__device__ __forceinline__ int reflect_i(int i, int n) {
  i = i < 0 ? -i : i;
  return i >= n ? 2 * (n - 1) - i : i;
}

// K1: depthwise 3x3, zero padding, for q/k/v in one pass.
__global__ void k_dw(const float* __restrict__ vid,
                     const float* __restrict__ qdw, const float* __restrict__ kdw,
                     const float* __restrict__ vdw, float* __restrict__ dw) {
  int plane = blockIdx.x;          // t*256+ch
  int ch = plane & 255;
  const float* src = vid + (size_t)plane * NPIX;
  float wq[9], wk[9], wv[9];
#pragma unroll
  for (int i = 0; i < 9; i++) { wq[i] = qdw[ch*9+i]; wk[i] = kdw[ch*9+i]; wv[i] = vdw[ch*9+i]; }
  int x = threadIdx.x, ty = threadIdx.y;   // (64,4)
  for (int yb = 0; yb < 16; ++yb) {
    int y = yb * 4 + ty;
    float aq = 0, ak = 0, av = 0;
#pragma unroll
    for (int a = 0; a < 3; a++) {
      int yy = y + a - 1;
      if (yy < 0 || yy >= HH) continue;
#pragma unroll
      for (int b = 0; b < 3; b++) {
        int xx = x + b - 1;
        if (xx < 0 || xx >= WW) continue;
        float xv = src[yy * WW + xx];
        aq += xv * wq[a*3+b]; ak += xv * wk[a*3+b]; av += xv * wv[a*3+b];
      }
    }
    size_t o = (size_t)plane * NPIX + y * WW + x;
    dw[o] = aq;
    dw[(size_t)3145728 + o] = ak;
    dw[(size_t)6291456 + o] = av;
  }
}

// K2 v7 (R16 best): 64x64 tile, 4x4 reg tile, dbuf + depth-2 reg pipeline.
// grid (64 pixtiles, 4 otiles, 9=type*3+t), block 256
__global__ void k_pw(const float* __restrict__ dw,
                     const float* __restrict__ qpw, const float* __restrict__ qb,
                     const float* __restrict__ kpw, const float* __restrict__ kb,
                     const float* __restrict__ vpw, const float* __restrict__ vb,
                     float* __restrict__ qo, float* __restrict__ ko, float* __restrict__ vo) {
  int type = blockIdx.z / 3, t = blockIdx.z % 3;
  const float* W   = type == 0 ? qpw : (type == 1 ? kpw : vpw);
  const float* bia = type == 0 ? qb  : (type == 1 ? kb  : vb);
  const float* A = dw + (size_t)type * 3145728 + (size_t)t * 1048576;  // [256][4096]
  int p0 = blockIdx.x * 64, o0 = blockIdx.y * 64;

  __shared__ float sW[2][16][68];   // [buf][k][o]
  __shared__ float sA[2][16][68];   // [buf][k][p]

  int tid = threadIdx.x;
  int ty = tid >> 4, tx = tid & 15;
  int wrow = tid >> 2, wcol = tid & 3;     // W staging: row 0..63, f4-col 0..3
  int arow = tid >> 4, acol = tid & 15;    // A staging: k-row 0..15, f4-px 0..15

  const float* Wp = &W[(size_t)(o0 + wrow) * 256 + wcol * 4];
  const float* Ap = &A[(size_t)arow * NPIX + p0 + acol * 4];

  {
    float4 w4 = *(const float4*)Wp;
    float4 a4 = *(const float4*)Ap;
    sW[0][wcol * 4 + 0][wrow] = w4.x;
    sW[0][wcol * 4 + 1][wrow] = w4.y;
    sW[0][wcol * 4 + 2][wrow] = w4.z;
    sW[0][wcol * 4 + 3][wrow] = w4.w;
    *(float4*)&sA[0][arow][acol * 4] = a4;
  }
  float4 wH = *(const float4*)(Wp + 16);
  float4 aH = *(const float4*)(Ap + (size_t)16 * NPIX);
  __syncthreads();

  float acc[4][4] = {};

#pragma unroll 1
  for (int k0 = 0; k0 < 256; k0 += 16) {
    const int cur = (k0 >> 4) & 1;
    float4 wN, aN;
    if (k0 + 32 < 256) {
      wN = *(const float4*)(Wp + k0 + 32);
      aN = *(const float4*)(Ap + (size_t)(k0 + 32) * NPIX);
    }
#pragma unroll
    for (int kk = 0; kk < 16; kk++) {
      float4 av = *(const float4*)&sW[cur][kk][ty * 4];
      float4 bv = *(const float4*)&sA[cur][kk][tx * 4];
      acc[0][0] += av.x * bv.x; acc[0][1] += av.x * bv.y; acc[0][2] += av.x * bv.z; acc[0][3] += av.x * bv.w;
      acc[1][0] += av.y * bv.x; acc[1][1] += av.y * bv.y; acc[1][2] += av.y * bv.z; acc[1][3] += av.y * bv.w;
      acc[2][0] += av.z * bv.x; acc[2][1] += av.z * bv.y; acc[2][2] += av.z * bv.z; acc[2][3] += av.z * bv.w;
      acc[3][0] += av.w * bv.x; acc[3][1] += av.w * bv.y; acc[3][2] += av.w * bv.z; acc[3][3] += av.w * bv.w;
    }
    if (k0 + 16 < 256) {
      const int nxt = cur ^ 1;
      sW[nxt][wcol * 4 + 0][wrow] = wH.x;
      sW[nxt][wcol * 4 + 1][wrow] = wH.y;
      sW[nxt][wcol * 4 + 2][wrow] = wH.z;
      sW[nxt][wcol * 4 + 3][wrow] = wH.w;
      *(float4*)&sA[nxt][arow][acol * 4] = aH;
      __syncthreads();
      wH = wN; aH = aN;
    }
  }

  int obase = o0 + ty * 4, pbase = p0 + tx * 4;
  if (type == 2) {
#pragma unroll
    for (int j = 0; j < 4; j++) {
      float4 ov = make_float4(acc[0][j] + bia[obase + 0],
                              acc[1][j] + bia[obase + 1],
                              acc[2][j] + bia[obase + 2],
                              acc[3][j] + bia[obase + 3]);
      *(float4*)&vo[((size_t)t * NPIX + pbase + j) * 256 + obase] = ov;
    }
  } else {
    float* dst = (type == 0) ? qo : ko;
    float sc = (type == 0) ? SCALE : 1.0f;
#pragma unroll
    for (int i = 0; i < 4; i++) {
      float bb = bia[obase + i];
      float4 ov = make_float4((acc[i][0] + bb) * sc, (acc[i][1] + bb) * sc,
                              (acc[i][2] + bb) * sc, (acc[i][3] + bb) * sc);
      *(float4*)&dst[((size_t)t * 256 + obase + i) * NPIX + pbase] = ov;
    }
  }
}

// K3a v2: q in REGISTERS; K staged per dyi into [cc][x] float4 LDS.
// grid 768 = th*64 + y, block 256
__global__ void k_dist(const float* __restrict__ q, const float* __restrict__ k,
                       float* __restrict__ D) {
  int b = blockIdx.x;
  int y = b & 63, th = b >> 6;
  int t = th >> 2, h = th & 3;
  __shared__ float4 sK4[16][64];   // [cc][x]
  int tid = threadIdx.x;
  int x = tid & 63, w = tid >> 6;
  const float* qp = q + ((size_t)t * 256 + h * 64) * NPIX + y * WW;
  const float* kp = k + ((size_t)t * 256 + h * 64) * NPIX;

  float4 qv[16];
#pragma unroll
  for (int cc = 0; cc < 16; cc++) {
    qv[cc].x = qp[(size_t)(4 * cc + 0) * NPIX + x];
    qv[cc].y = qp[(size_t)(4 * cc + 1) * NPIX + x];
    qv[cc].z = qp[(size_t)(4 * cc + 2) * NPIX + x];
    qv[cc].w = qp[(size_t)(4 * cc + 3) * NPIX + x];
  }

  for (int dyi = 0; dyi < 9; ++dyi) {
    int yk = reflect_i(y + dyi - 4, HH);
    __syncthreads();
    {
      int cc = tid >> 6;
      const float* kr = kp + (size_t)yk * WW;
#pragma unroll
      for (int r = 0; r < 4; r++) {
        int c4 = (cc + 4 * r) * 4;
        float4 kv;
        kv.x = kr[(size_t)(c4 + 0) * NPIX + x];
        kv.y = kr[(size_t)(c4 + 1) * NPIX + x];
        kv.z = kr[(size_t)(c4 + 2) * NPIX + x];
        kv.w = kr[(size_t)(c4 + 3) * NPIX + x];
        sK4[cc + 4 * r][x] = kv;
      }
    }
    __syncthreads();
    for (int dxi = w; dxi < 9; dxi += 4) {
      int xk = reflect_i(x + dxi - 4, WW);
      float s0 = 0.f, s1 = 0.f, s2 = 0.f, s3 = 0.f;
#pragma unroll
      for (int cc = 0; cc < 16; cc++) {
        float4 kv = sK4[cc][xk];
        s0 += qv[cc].x * kv.x;
        s1 += qv[cc].y * kv.y;
        s2 += qv[cc].z * kv.z;
        s3 += qv[cc].w * kv.w;
      }
      D[((size_t)(dyi * 9 + dxi) * 12 + th) * NPIX + y * WW + x] = (s0 + s1) + (s2 + s3);
    }
  }
}

// K3b v2: separable 7x7 reflected box sum. grid (12, 81), block 256
__global__ void k_box(const float* __restrict__ D, float* __restrict__ DG) {
  int th = blockIdx.x, n = blockIdx.y;
  int t = th >> 2, h = th & 3;
  __shared__ float sD[4096];
  __shared__ float sR[64][33];   // [y][gx], padded
  int tid = threadIdx.x;
  const float* Dp = D + ((size_t)n * 12 + th) * NPIX;
  for (int i = tid; i < 4096; i += 256) sD[i] = Dp[i];
  __syncthreads();
  for (int e = tid; e < 2048; e += 256) {
    int y = e >> 5, gx = e & 31;
    int xq = gx * 2;
    const float* row = sD + y * WW;
    float s = 0.f;
#pragma unroll
    for (int px = 0; px < 7; px++) {
      int rx = xq + px; rx = rx >= WW ? 126 - rx : rx;
      s += row[rx];
    }
    sR[y][gx] = s;
  }
  __syncthreads();
  for (int qi = tid; qi < 1024; qi += 256) {
    int gy = qi >> 5, gx = qi & 31;
    int yq = gy * 2;
    float s = 0.f;
#pragma unroll
    for (int py = 0; py < 7; py++) {
      int ry = yq + py; ry = ry >= HH ? 126 - ry : ry;
      s += sR[ry][gx];
    }
    DG[((size_t)h * QTOT + t * 1024 + qi) * NOFF + n] = s;
  }
}

// K3c v2: wave-parallel top-16 + softmax. grid 3072, block 256
__global__ void k_topk(const float* __restrict__ DG, float* __restrict__ attn,
                       int* __restrict__ inds) {
  int lane = threadIdx.x & 63;
  int r = blockIdx.x * 4 + (threadIdx.x >> 6);
  const float* row = DG + (size_t)r * NOFF;

  float v0 = row[lane];
  float v1 = (lane < NOFF - 64) ? row[64 + lane] : 0.f;

  auto mono = [](float f) -> unsigned {
    unsigned b = __float_as_uint(f);
    return (b & 0x80000000u) ? ~b : (b | 0x80000000u);
  };
  unsigned long long k0 = ((unsigned long long)mono(v0) << 7) | (unsigned)(127 - lane);
  unsigned long long k1 = (lane < NOFF - 64)
      ? (((unsigned long long)mono(v1) << 7) | (unsigned)(127 - 64 - lane))
      : 0ull;

  float vals[KS]; int idx[KS];
#pragma unroll
  for (int s = 0; s < KS; s++) {
    unsigned long long k = k0 > k1 ? k0 : k1;
#pragma unroll
    for (int m = 32; m >= 1; m >>= 1) {
      unsigned long long o = __shfl_xor(k, m, 64);
      if (o > k) k = o;
    }
    int wi = 127 - (int)(k & 127);
    unsigned mb = (unsigned)(k >> 7);
    unsigned vb = (mb & 0x80000000u) ? (mb ^ 0x80000000u) : ~mb;
    vals[s] = __uint_as_float(vb);
    idx[s] = wi;
    if (wi == lane) k0 = 0ull;
    else if (wi == 64 + lane) k1 = 0ull;
  }

  if (lane == 0) {
    float m = vals[0], den = 0.f, e[KS];
#pragma unroll
    for (int s = 0; s < KS; s++) { e[s] = expf(vals[s] - m); den += e[s]; }
    float inv = 1.f / den;
#pragma unroll
    for (int s = 0; s < KA; s++) {
      attn[(size_t)r * KA + s] = e[s] * inv;
      inds[(size_t)r * KA + s] = idx[s];
    }
  }
}

// K4 v7: gather aggregation (R8 v4 inner loop, 36 VGPR) + XCD swizzle.
// grid 3072 -> (xg, y, t); block 256 = 4 waves; lane owns 4 channels (float4).
#define NW 7
__global__ void k_agg(const float* __restrict__ v, const float* __restrict__ attn,
                      const int* __restrict__ inds, float* __restrict__ vacc) {
  // bijective XCD swizzle: 3072 blocks, 8 XCDs, 384 contiguous per XCD
  int bid = blockIdx.x;
  int swz = (bid & 7) * 384 + (bid >> 3);
  int xg = swz & 15, y = (swz >> 4) & 63, t = swz >> 10;
  int x0 = xg * 4;

  // y cover list (block-uniform)
  int g0 = max(0, (y - 5) >> 1), g1 = y >> 1;
  int ndir = g1 - g0 + 1;
  int yr = 126 - y;
  int r0 = (yr - 5) >> 1;
  int ny = ndir + (y >= 58 ? (min(31, yr >> 1) - r0 + 1) : 0);

  // gx window covering direct (and reflected, if x0+3 >= 58) queries
  int gxw0 = max(0, (x0 - 5) >> 1);
  int gxw1 = (x0 + 3) >= 58 ? 31 : ((x0 + 3) >> 1);
  int nw = gxw1 - gxw0 + 1;   // <= 7

  __shared__ float wt[7][NW][4][8];   // weight
  __shared__ int2  rc[7][NW][4][8];   // (row byte offset, col base pre-reflect)

  int tid = threadIdx.x;
  // prep: one entry per thread (<= 7*7*4 = 196 entries)
  {
    int iy = tid / (NW * 4);
    int rem = tid - iy * (NW * 4);
    int gxi = rem >> 2, h = rem & 3;
    if (iy < ny && gxi < nw) {
      int gy, py;
      if (iy < ndir) { gy = g0 + iy; py = y - 2 * gy; }
      else           { gy = r0 + (iy - ndir); py = yr - 2 * gy; }
      int gx = gxw0 + gxi;
      size_t r = (size_t)(h * QTOT + t * 1024 + gy * 32 + gx);
      float4 w0 = *(const float4*)(attn + r * KA);
      float4 w1 = *(const float4*)(attn + r * KA + 4);
      int4 i0 = *(const int4*)(inds + r * KA);
      int4 i1 = *(const int4*)(inds + r * KA + 4);
      int ids[8] = {i0.x, i0.y, i0.z, i0.w, i1.x, i1.y, i1.z, i1.w};
      float ww[8] = {w0.x, w0.y, w0.z, w0.w, w1.x, w1.y, w1.z, w1.w};
#pragma unroll
      for (int n = 0; n < 8; n++) {
        int dy = ids[n] / 9 - 4, dx = ids[n] % 9 - 4;
        int row = 2 * gy + dy + py;
        row = row < 0 ? -row : row;
        row = min(row, 126 - row);
        wt[iy][gxi][h][n] = ww[n];
        rc[iy][gxi][h][n] = make_int2(row << 16, 2 * gx + dx);
      }
    }
  }
  __syncthreads();

  int wv = tid >> 6, lane = tid & 63;
  int x = x0 + wv;
  int h = lane >> 4;
  const char* vB = (const char*)v + (size_t)t * ((size_t)NPIX * DIMD * 4)
                   + (unsigned)(lane * 16);

  int a0 = max(0, (x - 5) >> 1), a1 = x >> 1;
  int xr = 126 - x;
  int b0 = (xr - 5) >> 1, b1 = min(31, xr >> 1);
  bool has_refl = (x >= 58);

  float4 acc = make_float4(0.f, 0.f, 0.f, 0.f);
  for (int iy = 0; iy < ny; ++iy) {
    for (int g = a0; g <= a1; ++g) {
      int gxi = g - gxw0, px = x - 2 * g;
      const float* w8 = wt[iy][gxi][h];
      const int2* r8 = rc[iy][gxi][h];
#pragma unroll
      for (int n = 0; n < 8; n++) {
        float w = w8[n]; int2 e = r8[n];
        int col = e.y + px;
        col = col < 0 ? -col : col;
        col = min(col, 126 - col);
        float4 vv = *(const float4*)(vB + (unsigned)(e.x + (col << 10)));
        acc.x += w * vv.x; acc.y += w * vv.y; acc.z += w * vv.z; acc.w += w * vv.w;
      }
    }
    if (has_refl) {
      for (int g = b0; g <= b1; ++g) {
        int gxi = g - gxw0, px = xr - 2 * g;
        const float* w8 = wt[iy][gxi][h];
        const int2* r8 = rc[iy][gxi][h];
#pragma unroll
        for (int n = 0; n < 8; n++) {
          float w = w8[n]; int2 e = r8[n];
          int col = e.y + px;
          col = col < 0 ? -col : col;
          col = min(col, 126 - col);
          float4 vv = *(const float4*)(vB + (unsigned)(e.x + (col << 10)));
          acc.x += w * vv.x; acc.y += w * vv.y; acc.z += w * vv.z; acc.w += w * vv.w;
        }
      }
    }
  }
  float* oP = vacc + ((size_t)t * NPIX + (size_t)y * WW + x) * DIMD + lane * 4;
  *(float4*)oP = acc;
}

// coverage count for one axis (how many (g,p) pairs map to index i)
__device__ __forceinline__ int cov_count(int i) {
  int d = (i >> 1) - max(0, (i - 5) >> 1) + 1;
  if (i >= 58) { int r = 126 - i; d += min(31, r >> 1) - ((r - 5) >> 1) + 1; }
  return d;
}

// K5 v4: final projection, 64x64 tile, 4x4 reg tile, dbuf rolled.
// grid (192, 4), block 256
__global__ void k_proj(const float* __restrict__ vacc,
                       const float* __restrict__ pw, const float* __restrict__ pb,
                       float* __restrict__ out) {
  int p0 = blockIdx.x * 64;  // global pixel (t*4096 + y*64 + x)
  int d0 = blockIdx.y * 64;

  __shared__ float sW[2][16][68];   // [buf][k][d]
  __shared__ float sV[2][16][68];   // [buf][k][p]

  int tid = threadIdx.x;
  int ty = tid >> 4, tx = tid & 15;
  int row = tid >> 2, col = tid & 3;   // staging: row 0..63, f4-col 0..3

  const float* Wp = &pw[(size_t)(d0 + row) * 256 + col * 4];
  const float* Vp = &vacc[(size_t)(p0 + row) * 256 + col * 4];

  {
    float4 w4 = *(const float4*)Wp;
    float4 v4 = *(const float4*)Vp;
    sW[0][col * 4 + 0][row] = w4.x;
    sW[0][col * 4 + 1][row] = w4.y;
    sW[0][col * 4 + 2][row] = w4.z;
    sW[0][col * 4 + 3][row] = w4.w;
    sV[0][col * 4 + 0][row] = v4.x;
    sV[0][col * 4 + 1][row] = v4.y;
    sV[0][col * 4 + 2][row] = v4.z;
    sV[0][col * 4 + 3][row] = v4.w;
  }
  __syncthreads();

  float acc[4][4] = {};

#pragma unroll 1
  for (int k0 = 0; k0 < 256; k0 += 16) {
    const int cur = (k0 >> 4) & 1;
    const bool hn = (k0 + 16) < 256;
    float4 w4n, v4n;
    if (hn) {
      w4n = *(const float4*)(Wp + k0 + 16);
      v4n = *(const float4*)(Vp + k0 + 16);
    }
#pragma unroll
    for (int kk = 0; kk < 16; kk++) {
      float4 av = *(const float4*)&sW[cur][kk][ty * 4];
      float4 bv = *(const float4*)&sV[cur][kk][tx * 4];
      acc[0][0] += av.x * bv.x; acc[0][1] += av.x * bv.y; acc[0][2] += av.x * bv.z; acc[0][3] += av.x * bv.w;
      acc[1][0] += av.y * bv.x; acc[1][1] += av.y * bv.y; acc[1][2] += av.y * bv.z; acc[1][3] += av.y * bv.w;
      acc[2][0] += av.z * bv.x; acc[2][1] += av.z * bv.y; acc[2][2] += av.z * bv.z; acc[2][3] += av.z * bv.w;
      acc[3][0] += av.w * bv.x; acc[3][1] += av.w * bv.y; acc[3][2] += av.w * bv.z; acc[3][3] += av.w * bv.w;
    }
    if (hn) {
      const int nxt = cur ^ 1;
      sW[nxt][col * 4 + 0][row] = w4n.x;
      sW[nxt][col * 4 + 1][row] = w4n.y;
      sW[nxt][col * 4 + 2][row] = w4n.z;
      sW[nxt][col * 4 + 3][row] = w4n.w;
      sV[nxt][col * 4 + 0][row] = v4n.x;
      sV[nxt][col * 4 + 1][row] = v4n.y;
      sV[nxt][col * 4 + 2][row] = v4n.z;
      sV[nxt][col * 4 + 3][row] = v4n.w;
      __syncthreads();
    }
  }

  int dbase = d0 + ty * 4, pbase = p0 + tx * 4;
  float izv[4];
#pragma unroll
  for (int j = 0; j < 4; j++) {
    int pl = (pbase + j) & 4095;
    int yy = pl >> 6, xx = pl & 63;
    izv[j] = 1.0f / (float)(cov_count(yy) * cov_count(xx));
  }
  int t = pbase >> 12, pl0 = pbase & 4095;
#pragma unroll
  for (int i = 0; i < 4; i++) {
    int d = dbase + i;
    float bb = pb[d];
    float4 ov = make_float4(acc[i][0] * izv[0] + bb, acc[i][1] * izv[1] + bb,
                            acc[i][2] * izv[2] + bb, acc[i][3] * izv[3] + bb);
    *(float4*)&out[((size_t)t * 256 + d) * NPIX + pl0] = ov;
  }
}

extern "C" void kernel_launch(void* const* d_in, const int* in_sizes, int n_in,
                              void* d_out, int out_size, void* d_ws, size_t ws_size,
                              hipStream_t stream) {
  const float* vid = (const float*)d_in[0];
  const float* qdw = (const float*)d_in[1];
  const float* qpw = (const float*)d_in[2];
  const float* qb  = (const float*)d_in[3];
  const float* kdw = (const float*)d_in[4];
  const float* kpw = (const float*)d_in[5];
  const float* kb  = (const float*)d_in[6];
  const float* vdw = (const float*)d_in[7];
  const float* vpw = (const float*)d_in[8];
  const float* vb  = (const float*)d_in[9];
  const float* pw  = (const float*)d_in[10];
  const float* pb  = (const float*)d_in[11];
  float* out = (float*)d_out;
  float* ws = (float*)d_ws;

  float* dwb  = ws + OFF_DW;
  float* qbuf = ws + OFF_Q;
  float* kbuf = ws + OFF_K;
  float* vbuf = ws + OFF_V;
  float* Dbuf = ws + OFF_D;
  float* DG   = ws + OFF_DG;
  float* attn = ws + OFF_ATTN;
  int*   inds = (int*)(ws + OFF_INDS);
  float* vacc = ws + OFF_VACC;

  k_dw<<<dim3(768), dim3(64, 4), 0, stream>>>(vid, qdw, kdw, vdw, dwb);
  k_pw<<<dim3(64, 4, 9), 256, 0, stream>>>(dwb, qpw, qb, kpw, kb, vpw, vb,
                                           qbuf, kbuf, vbuf);
  k_dist<<<dim3(768), 256, 0, stream>>>(qbuf, kbuf, Dbuf);
  k_box<<<dim3(12, 81), 256, 0, stream>>>(Dbuf, DG);
  k_topk<<<dim3(3072), 256, 0, stream>>>(DG, attn, inds);
  k_agg<<<dim3(3072), 256, 0, stream>>>(vbuf, attn, inds, vacc);
  k_proj<<<dim3(192, 4), 256, 0, stream>>>(vacc, pw, pb, out);
}